// Round 1
// baseline (499.805 us; speedup 1.0000x reference)
//
#include <hip/hip_runtime.h>
#include <math.h>

#define B_ 64
#define T_ 4096
#define D_ 256
#define U_ 64
#define TCHUNK 128

// Pass 1: logits[b,t] = tanh(x[b,t,:] @ W + b) @ u
// One thread per (b,t). 64 fp32 accumulators; W/bias/u are wave-uniform reads.
__global__ __launch_bounds__(256) void logits_kernel(
    const float* __restrict__ x, const float* __restrict__ W,
    const float* __restrict__ bias, const float* __restrict__ uvec,
    float* __restrict__ logits)
{
    int t = blockIdx.x * 256 + threadIdx.x;   // global (b*T + t), grid exactly covers B*T
    const float* xp = x + (size_t)t * D_;
    const float4* xv4 = (const float4*)xp;

    float acc[U_];
#pragma unroll
    for (int u = 0; u < U_; ++u) acc[u] = 0.f;

    for (int d4 = 0; d4 < D_ / 4; ++d4) {
        float4 xv = xv4[d4];
        const float* wrow = W + d4 * 4 * U_;   // uniform address -> scalar/broadcast loads
#pragma unroll
        for (int j = 0; j < 4; ++j) {
            float xd = (j == 0) ? xv.x : (j == 1) ? xv.y : (j == 2) ? xv.z : xv.w;
#pragma unroll
            for (int u = 0; u < U_; ++u)
                acc[u] = fmaf(xd, wrow[j * U_ + u], acc[u]);
        }
    }

    float logit = 0.f;
#pragma unroll
    for (int u = 0; u < U_; ++u) {
        float v = acc[u] + bias[u];
        // tanh(v) = 1 - 2/(exp(2v)+1): stable for large |v| (inf -> 1, 0 -> -1)
        float s = 1.f - 2.f / (__expf(2.f * v) + 1.f);
        logit = fmaf(s, uvec[u], logit);
    }
    logits[t] = logit;
}

// Pass 2: in-place softmax over T for each batch. wts holds logits on entry.
__global__ __launch_bounds__(256) void softmax_kernel(float* __restrict__ wts)
{
    int b = blockIdx.x;
    float* wp = wts + (size_t)b * T_;
    int tid = threadIdx.x;
    int wave = tid >> 6, lane = tid & 63;

    float vals[T_ / 256];
#pragma unroll
    for (int i = 0; i < T_ / 256; ++i) vals[i] = wp[tid + i * 256];

    float m = -INFINITY;
#pragma unroll
    for (int i = 0; i < T_ / 256; ++i) m = fmaxf(m, vals[i]);
#pragma unroll
    for (int off = 32; off >= 1; off >>= 1)
        m = fmaxf(m, __shfl_down(m, off, 64));

    __shared__ float smax[4], ssum[4];
    if (lane == 0) smax[wave] = m;
    __syncthreads();
    if (tid == 0)
        smax[0] = fmaxf(fmaxf(smax[0], smax[1]), fmaxf(smax[2], smax[3]));
    __syncthreads();
    m = smax[0];

    float s = 0.f;
#pragma unroll
    for (int i = 0; i < T_ / 256; ++i) {
        vals[i] = __expf(vals[i] - m);
        s += vals[i];
    }
#pragma unroll
    for (int off = 32; off >= 1; off >>= 1)
        s += __shfl_down(s, off, 64);
    if (lane == 0) ssum[wave] = s;
    __syncthreads();
    if (tid == 0) ssum[0] = ssum[0] + ssum[1] + ssum[2] + ssum[3];
    __syncthreads();

    float inv = 1.f / ssum[0];
#pragma unroll
    for (int i = 0; i < T_ / 256; ++i) wp[tid + i * 256] = vals[i] * inv;
}

// Pass 3: context[b,d] = sum_t w[b,t] * x[b,t,d]. Block = (t-chunk, b), thread = d.
__global__ __launch_bounds__(256) void context_kernel(
    const float* __restrict__ x, const float* __restrict__ wts,
    float* __restrict__ ctx)
{
    int b = blockIdx.y;
    int t0 = blockIdx.x * TCHUNK;
    int d = threadIdx.x;
    const float* xp = x + ((size_t)b * T_ + t0) * D_ + d;
    const float* wp = wts + (size_t)b * T_ + t0;

    float acc = 0.f;
#pragma unroll 4
    for (int i = 0; i < TCHUNK; ++i)
        acc = fmaf(wp[i], xp[(size_t)i * D_], acc);   // wp[i] uniform -> s_load

    atomicAdd(&ctx[b * D_ + d], acc);
}

extern "C" void kernel_launch(void* const* d_in, const int* in_sizes, int n_in,
                              void* d_out, int out_size, void* d_ws, size_t ws_size,
                              hipStream_t stream) {
    const float* x    = (const float*)d_in[0];   // [B,T,D]
    const float* W    = (const float*)d_in[1];   // [D,U]
    const float* bias = (const float*)d_in[2];   // [U]
    const float* uvec = (const float*)d_in[3];   // [U,1]

    float* out = (float*)d_out;
    float* ctx = out;            // context: B*D floats
    float* wts = out + B_ * D_;  // attention weights: B*T floats (also holds logits between passes)

    // zero the context accumulator region (harness poisons d_out with 0xAA)
    hipMemsetAsync(ctx, 0, B_ * D_ * sizeof(float), stream);

    logits_kernel<<<(B_ * T_) / 256, 256, 0, stream>>>(x, W, bias, uvec, wts);
    softmax_kernel<<<B_, 256, 0, stream>>>(wts);
    context_kernel<<<dim3(T_ / TCHUNK, B_), 256, 0, stream>>>(x, wts, ctx);
}

// Round 2
// 457.972 us; speedup vs baseline: 1.0913x; 1.0913x over previous
//
#include <hip/hip_runtime.h>
#include <math.h>

#define B_ 64
#define T_ 4096
#define D_ 256
#define U_ 64
#define TM 64            // rows of x per block in logits_mfma
#define ASTRIDE 264      // LDS row stride in bf16 elems (256 + 8 pad)
#define TC 256           // t-chunk per context block

typedef float f32x4 __attribute__((ext_vector_type(4)));
typedef short bf16x8 __attribute__((ext_vector_type(8)));

__device__ __forceinline__ unsigned short f2bf_rne(float f) {
    unsigned u = __float_as_uint(f);
    unsigned r = u + 0x7fffu + ((u >> 16) & 1u);
    return (unsigned short)(r >> 16);
}
__device__ __forceinline__ float bfbits2f(unsigned short s) {
    return __uint_as_float(((unsigned)s) << 16);
}

// Pack W [D,U] fp32 into MFMA B-fragment order, split hi/lo bf16.
// Fragment (ks,nt,lane,j): value = W[k = ks*32 + (lane>>4)*8 + j][n = nt*16 + (lane&15)]
// flat elem index fi = ((ks*4+nt)*64 + lane)*8 + j  -> lane reads 16B coalesced.
__global__ __launch_bounds__(256) void wprep_kernel(
    const float* __restrict__ W, unsigned short* __restrict__ whi,
    unsigned short* __restrict__ wlo)
{
    int fi = blockIdx.x * 256 + threadIdx.x;   // 0..16383, grid=64
    int j    = fi & 7;
    int lane = (fi >> 3) & 63;
    int tile = fi >> 9;            // 0..31
    int nt = tile & 3, ks = tile >> 2;
    int k = ks * 32 + (lane >> 4) * 8 + j;
    int n = nt * 16 + (lane & 15);
    float w = W[k * U_ + n];
    unsigned short hi = f2bf_rne(w);
    unsigned short lo = f2bf_rne(w - bfbits2f(hi));
    whi[fi] = hi;
    wlo[fi] = lo;
}

// Pass 1: logits[b,t] = tanh(x@W + b) @ u  via split-bf16 MFMA 16x16x32.
// Block = 256 threads (4 waves), TM=64 rows; wave w owns rows [w*16, w*16+16).
__global__ __launch_bounds__(256) void logits_mfma(
    const float* __restrict__ x, const unsigned short* __restrict__ whi,
    const unsigned short* __restrict__ wlo, const float* __restrict__ bias,
    const float* __restrict__ uvec, float* __restrict__ logits)
{
    __shared__ unsigned short Ahi[TM * ASTRIDE];
    __shared__ unsigned short Alo[TM * ASTRIDE];

    int tid = threadIdx.x;
    const float4* xb = (const float4*)(x + (size_t)blockIdx.x * TM * D_);

    // ---- stage x rows -> bf16 hi/lo in LDS (row-major, padded) ----
#pragma unroll
    for (int i = 0; i < 16; ++i) {
        int f = tid + i * 256;            // float4 index, 0..4095
        int row = f >> 6, c4 = f & 63;
        float4 v = xb[f];
        unsigned short h0 = f2bf_rne(v.x), h1 = f2bf_rne(v.y),
                       h2 = f2bf_rne(v.z), h3 = f2bf_rne(v.w);
        unsigned short l0 = f2bf_rne(v.x - bfbits2f(h0)),
                       l1 = f2bf_rne(v.y - bfbits2f(h1)),
                       l2 = f2bf_rne(v.z - bfbits2f(h2)),
                       l3 = f2bf_rne(v.w - bfbits2f(h3));
        int base = row * ASTRIDE + c4 * 4;
        uint2 hp = { (unsigned)h0 | ((unsigned)h1 << 16),
                     (unsigned)h2 | ((unsigned)h3 << 16) };
        uint2 lp = { (unsigned)l0 | ((unsigned)l1 << 16),
                     (unsigned)l2 | ((unsigned)l3 << 16) };
        *(uint2*)(&Ahi[base]) = hp;
        *(uint2*)(&Alo[base]) = lp;
    }
    __syncthreads();

    // ---- MFMA main loop ----
    int lane = tid & 63, wid = tid >> 6;
    int q = lane >> 4, r = lane & 15;

    f32x4 acc[4];
#pragma unroll
    for (int nt = 0; nt < 4; ++nt) acc[nt] = (f32x4){0.f, 0.f, 0.f, 0.f};

    const bf16x8* whiV = (const bf16x8*)whi;
    const bf16x8* wloV = (const bf16x8*)wlo;

#pragma unroll
    for (int ks = 0; ks < 8; ++ks) {
        int aoff = (wid * 16 + r) * ASTRIDE + ks * 32 + q * 8;
        bf16x8 ahi = *(const bf16x8*)(&Ahi[aoff]);
        bf16x8 alo = *(const bf16x8*)(&Alo[aoff]);
#pragma unroll
        for (int nt = 0; nt < 4; ++nt) {
            bf16x8 bhi = whiV[(ks * 4 + nt) * 64 + lane];
            bf16x8 blo = wloV[(ks * 4 + nt) * 64 + lane];
            acc[nt] = __builtin_amdgcn_mfma_f32_16x16x32_bf16(ahi, bhi, acc[nt], 0, 0, 0);
            acc[nt] = __builtin_amdgcn_mfma_f32_16x16x32_bf16(ahi, blo, acc[nt], 0, 0, 0);
            acc[nt] = __builtin_amdgcn_mfma_f32_16x16x32_bf16(alo, bhi, acc[nt], 0, 0, 0);
        }
    }

    // ---- epilogue: score=tanh(acc+bias); partial logit = score*u; reduce over n-lanes ----
    // C/D layout: row = q*4 + reg (within 16-row strip), col = nt*16 + r.
    float p0 = 0.f, p1 = 0.f, p2 = 0.f, p3 = 0.f;
#pragma unroll
    for (int nt = 0; nt < 4; ++nt) {
        int col = nt * 16 + r;
        float bv = bias[col], uv = uvec[col];
        float s0 = acc[nt][0] + bv, s1 = acc[nt][1] + bv,
              s2 = acc[nt][2] + bv, s3 = acc[nt][3] + bv;
        // tanh(v) = 1 - 2/(exp(2v)+1), stable
        p0 = fmaf(1.f - 2.f / (__expf(2.f * s0) + 1.f), uv, p0);
        p1 = fmaf(1.f - 2.f / (__expf(2.f * s1) + 1.f), uv, p1);
        p2 = fmaf(1.f - 2.f / (__expf(2.f * s2) + 1.f), uv, p2);
        p3 = fmaf(1.f - 2.f / (__expf(2.f * s3) + 1.f), uv, p3);
    }
#pragma unroll
    for (int off = 1; off < 16; off <<= 1) {
        p0 += __shfl_xor(p0, off, 64);
        p1 += __shfl_xor(p1, off, 64);
        p2 += __shfl_xor(p2, off, 64);
        p3 += __shfl_xor(p3, off, 64);
    }
    if (r == 0) {
        float4 o = {p0, p1, p2, p3};
        *(float4*)(logits + (size_t)blockIdx.x * TM + wid * 16 + q * 4) = o;
    }
}

// Pass 2: in-place softmax over T per batch.
__global__ __launch_bounds__(256) void softmax_kernel(float* __restrict__ wts)
{
    int b = blockIdx.x;
    float* wp = wts + (size_t)b * T_;
    int tid = threadIdx.x;
    int wave = tid >> 6, lane = tid & 63;

    float vals[T_ / 256];
#pragma unroll
    for (int i = 0; i < T_ / 256; ++i) vals[i] = wp[tid + i * 256];

    float m = -INFINITY;
#pragma unroll
    for (int i = 0; i < T_ / 256; ++i) m = fmaxf(m, vals[i]);
#pragma unroll
    for (int off = 32; off >= 1; off >>= 1)
        m = fmaxf(m, __shfl_down(m, off, 64));

    __shared__ float smax[4], ssum[4];
    if (lane == 0) smax[wave] = m;
    __syncthreads();
    if (tid == 0)
        smax[0] = fmaxf(fmaxf(smax[0], smax[1]), fmaxf(smax[2], smax[3]));
    __syncthreads();
    m = smax[0];

    float s = 0.f;
#pragma unroll
    for (int i = 0; i < T_ / 256; ++i) {
        vals[i] = __expf(vals[i] - m);
        s += vals[i];
    }
#pragma unroll
    for (int off = 32; off >= 1; off >>= 1)
        s += __shfl_down(s, off, 64);
    if (lane == 0) ssum[wave] = s;
    __syncthreads();
    if (tid == 0) ssum[0] = ssum[0] + ssum[1] + ssum[2] + ssum[3];
    __syncthreads();

    float inv = 1.f / ssum[0];
#pragma unroll
    for (int i = 0; i < T_ / 256; ++i) wp[tid + i * 256] = vals[i] * inv;
}

// Pass 3: context[b,d] = sum_t w[b,t]*x[b,t,d]. 8 independent accumulators,
// 8 loads in flight. Grid (T/TC, B), thread = d.
__global__ __launch_bounds__(256) void context_kernel(
    const float* __restrict__ x, const float* __restrict__ wts,
    float* __restrict__ ctx)
{
    int b = blockIdx.y;
    int t0 = blockIdx.x * TC;
    int d = threadIdx.x;
    const float* xp = x + ((size_t)b * T_ + t0) * D_ + d;
    const float* wp = wts + (size_t)b * T_ + t0;

    float acc[8];
#pragma unroll
    for (int j = 0; j < 8; ++j) acc[j] = 0.f;

    for (int i = 0; i < TC; i += 8) {
        float w[8], xv[8];
#pragma unroll
        for (int j = 0; j < 8; ++j) w[j] = wp[i + j];          // uniform -> s_load
#pragma unroll
        for (int j = 0; j < 8; ++j) xv[j] = xp[(size_t)(i + j) * D_];
#pragma unroll
        for (int j = 0; j < 8; ++j) acc[j] = fmaf(w[j], xv[j], acc[j]);
    }
    float s = ((acc[0] + acc[1]) + (acc[2] + acc[3])) +
              ((acc[4] + acc[5]) + (acc[6] + acc[7]));
    atomicAdd(&ctx[b * D_ + d], s);
}

extern "C" void kernel_launch(void* const* d_in, const int* in_sizes, int n_in,
                              void* d_out, int out_size, void* d_ws, size_t ws_size,
                              hipStream_t stream) {
    const float* x    = (const float*)d_in[0];   // [B,T,D]
    const float* W    = (const float*)d_in[1];   // [D,U]
    const float* bias = (const float*)d_in[2];   // [U]
    const float* uvec = (const float*)d_in[3];   // [U,1]

    float* out = (float*)d_out;
    float* ctx = out;            // context: B*D floats
    float* wts = out + B_ * D_;  // attention weights: B*T floats (holds logits between passes)

    unsigned short* whi = (unsigned short*)d_ws;          // 32 KB
    unsigned short* wlo = whi + D_ * U_;                  // 32 KB

    hipMemsetAsync(ctx, 0, B_ * D_ * sizeof(float), stream);

    wprep_kernel<<<D_ * U_ / 256, 256, 0, stream>>>(W, whi, wlo);
    logits_mfma<<<(B_ * T_) / TM, 256, 0, stream>>>(x, whi, wlo, bias, uvec, wts);
    softmax_kernel<<<B_, 256, 0, stream>>>(wts);
    context_kernel<<<dim3(T_ / TC, B_), 256, 0, stream>>>(x, wts, ctx);
}

// Round 3
// 424.303 us; speedup vs baseline: 1.1779x; 1.0794x over previous
//
#include <hip/hip_runtime.h>
#include <math.h>

#define B_ 64
#define T_ 4096
#define D_ 256
#define U_ 64
#define TM 64            // rows of x per block in logits_mfma (4 waves x 16)
#define TC 256           // t-chunk per context block

typedef float f32x4 __attribute__((ext_vector_type(4)));
typedef short bf16x8 __attribute__((ext_vector_type(8)));

__device__ __forceinline__ unsigned short f2bf_rne(float f) {
    unsigned u = __float_as_uint(f);
    unsigned r = u + 0x7fffu + ((u >> 16) & 1u);
    return (unsigned short)(r >> 16);
}
__device__ __forceinline__ float bfbits2f(unsigned short s) {
    return __uint_as_float(((unsigned)s) << 16);
}

// Pack W [D,U] fp32 into MFMA B-fragment order, split hi/lo bf16.
// Fragment (ks,nt,lane,j): value = W[k = ks*32 + (lane>>4)*8 + j][n = nt*16 + (lane&15)]
__global__ __launch_bounds__(256) void wprep_kernel(
    const float* __restrict__ W, unsigned short* __restrict__ whi,
    unsigned short* __restrict__ wlo)
{
    int fi = blockIdx.x * 256 + threadIdx.x;   // 0..16383, grid=64
    int j    = fi & 7;
    int lane = (fi >> 3) & 63;
    int tile = fi >> 9;            // 0..31
    int nt = tile & 3, ks = tile >> 2;
    int k = ks * 32 + (lane >> 4) * 8 + j;
    int n = nt * 16 + (lane & 15);
    float w = W[k * U_ + n];
    unsigned short hi = f2bf_rne(w);
    unsigned short lo = f2bf_rne(w - bfbits2f(hi));
    whi[fi] = hi;
    wlo[fi] = lo;
}

// Pass 1: logits[b,t] = tanh(x@W + b) @ u  via split-bf16 MFMA 16x16x32.
// No LDS: A-fragments load straight from row-major x (lanes r,r+16,r+32,r+48
// cover a contiguous 128B of row r), converted to bf16 hi/lo in registers.
__global__ __launch_bounds__(256) void logits_mfma(
    const float* __restrict__ x, const unsigned short* __restrict__ whi,
    const unsigned short* __restrict__ wlo, const float* __restrict__ bias,
    const float* __restrict__ uvec, float* __restrict__ logits)
{
    int tid = threadIdx.x;
    int lane = tid & 63, wid = tid >> 6;
    int q = lane >> 4, r = lane & 15;

    size_t row = (size_t)blockIdx.x * TM + wid * 16 + r;
    const float* xrow = x + row * D_;

    f32x4 acc[4];
#pragma unroll
    for (int nt = 0; nt < 4; ++nt) acc[nt] = (f32x4){0.f, 0.f, 0.f, 0.f};

    const bf16x8* whiV = (const bf16x8*)whi;
    const bf16x8* wloV = (const bf16x8*)wlo;

#pragma unroll
    for (int ks = 0; ks < 8; ++ks) {
        int k0 = ks * 32 + q * 8;
        float4 va = *(const float4*)(xrow + k0);
        float4 vb = *(const float4*)(xrow + k0 + 4);
        float f[8] = {va.x, va.y, va.z, va.w, vb.x, vb.y, vb.z, vb.w};
        union { bf16x8 v; unsigned short s[8]; } ahi, alo;
#pragma unroll
        for (int j = 0; j < 8; ++j) {
            unsigned short h = f2bf_rne(f[j]);
            ahi.s[j] = h;
            alo.s[j] = f2bf_rne(f[j] - bfbits2f(h));
        }
#pragma unroll
        for (int nt = 0; nt < 4; ++nt) {
            bf16x8 bhi = whiV[(ks * 4 + nt) * 64 + lane];
            bf16x8 blo = wloV[(ks * 4 + nt) * 64 + lane];
            acc[nt] = __builtin_amdgcn_mfma_f32_16x16x32_bf16(ahi.v, bhi, acc[nt], 0, 0, 0);
            acc[nt] = __builtin_amdgcn_mfma_f32_16x16x32_bf16(ahi.v, blo, acc[nt], 0, 0, 0);
            acc[nt] = __builtin_amdgcn_mfma_f32_16x16x32_bf16(alo.v, bhi, acc[nt], 0, 0, 0);
        }
    }

    // Epilogue: score=tanh(acc+bias); partial logit = score*u; reduce over n-lanes.
    // C/D layout: row = q*4 + reg, col = nt*16 + r.
    float p0 = 0.f, p1 = 0.f, p2 = 0.f, p3 = 0.f;
#pragma unroll
    for (int nt = 0; nt < 4; ++nt) {
        int col = nt * 16 + r;
        float bv = bias[col], uv = uvec[col];
        float s0 = acc[nt][0] + bv, s1 = acc[nt][1] + bv,
              s2 = acc[nt][2] + bv, s3 = acc[nt][3] + bv;
        p0 = fmaf(1.f - 2.f / (__expf(2.f * s0) + 1.f), uv, p0);
        p1 = fmaf(1.f - 2.f / (__expf(2.f * s1) + 1.f), uv, p1);
        p2 = fmaf(1.f - 2.f / (__expf(2.f * s2) + 1.f), uv, p2);
        p3 = fmaf(1.f - 2.f / (__expf(2.f * s3) + 1.f), uv, p3);
    }
#pragma unroll
    for (int off = 1; off < 16; off <<= 1) {
        p0 += __shfl_xor(p0, off, 64);
        p1 += __shfl_xor(p1, off, 64);
        p2 += __shfl_xor(p2, off, 64);
        p3 += __shfl_xor(p3, off, 64);
    }
    if (r == 0) {
        float4 o = {p0, p1, p2, p3};
        *(float4*)(logits + (size_t)blockIdx.x * TM + wid * 16 + q * 4) = o;
    }
}

// Pass 2: in-place softmax over T per batch.
__global__ __launch_bounds__(256) void softmax_kernel(float* __restrict__ wts)
{
    int b = blockIdx.x;
    float* wp = wts + (size_t)b * T_;
    int tid = threadIdx.x;
    int wave = tid >> 6, lane = tid & 63;

    float vals[T_ / 256];
#pragma unroll
    for (int i = 0; i < T_ / 256; ++i) vals[i] = wp[tid + i * 256];

    float m = -INFINITY;
#pragma unroll
    for (int i = 0; i < T_ / 256; ++i) m = fmaxf(m, vals[i]);
#pragma unroll
    for (int off = 32; off >= 1; off >>= 1)
        m = fmaxf(m, __shfl_down(m, off, 64));

    __shared__ float smax[4], ssum[4];
    if (lane == 0) smax[wave] = m;
    __syncthreads();
    if (tid == 0)
        smax[0] = fmaxf(fmaxf(smax[0], smax[1]), fmaxf(smax[2], smax[3]));
    __syncthreads();
    m = smax[0];

    float s = 0.f;
#pragma unroll
    for (int i = 0; i < T_ / 256; ++i) {
        vals[i] = __expf(vals[i] - m);
        s += vals[i];
    }
#pragma unroll
    for (int off = 32; off >= 1; off >>= 1)
        s += __shfl_down(s, off, 64);
    if (lane == 0) ssum[wave] = s;
    __syncthreads();
    if (tid == 0) ssum[0] = ssum[0] + ssum[1] + ssum[2] + ssum[3];
    __syncthreads();

    float inv = 1.f / ssum[0];
#pragma unroll
    for (int i = 0; i < T_ / 256; ++i) wp[tid + i * 256] = vals[i] * inv;
}

// Pass 3: context[b,d] = sum_t w[b,t]*x[b,t,d].
// Wave ts handles rows t ≡ ts (mod 4); lane d4 holds float4 column d4.
// 16B/lane loads (1KB/wave-instr), 4 independent float4 chains, uniform w -> s_load.
__global__ __launch_bounds__(256) void context_kernel(
    const float* __restrict__ x, const float* __restrict__ wts,
    float* __restrict__ ctx)
{
    int b = blockIdx.y;
    int t0 = blockIdx.x * TC;
    int tid = threadIdx.x;
    int d4 = tid & 63;     // float4 column
    int ts = tid >> 6;     // wave id = t phase

    const float4* xp = (const float4*)(x + ((size_t)b * T_ + t0) * D_) + d4;
    const float* wp = wts + (size_t)b * T_ + t0 + ts;

    float4 a0 = {0,0,0,0}, a1 = a0, a2 = a0, a3 = a0;
#pragma unroll 4
    for (int j = 0; j < TC / 4; j += 4) {
        float w0 = wp[4 * (j + 0)];
        float w1 = wp[4 * (j + 1)];
        float w2 = wp[4 * (j + 2)];
        float w3 = wp[4 * (j + 3)];
        float4 x0 = xp[(size_t)(ts + 4 * (j + 0)) * 64];
        float4 x1 = xp[(size_t)(ts + 4 * (j + 1)) * 64];
        float4 x2 = xp[(size_t)(ts + 4 * (j + 2)) * 64];
        float4 x3 = xp[(size_t)(ts + 4 * (j + 3)) * 64];
        a0.x = fmaf(w0, x0.x, a0.x); a0.y = fmaf(w0, x0.y, a0.y);
        a0.z = fmaf(w0, x0.z, a0.z); a0.w = fmaf(w0, x0.w, a0.w);
        a1.x = fmaf(w1, x1.x, a1.x); a1.y = fmaf(w1, x1.y, a1.y);
        a1.z = fmaf(w1, x1.z, a1.z); a1.w = fmaf(w1, x1.w, a1.w);
        a2.x = fmaf(w2, x2.x, a2.x); a2.y = fmaf(w2, x2.y, a2.y);
        a2.z = fmaf(w2, x2.z, a2.z); a2.w = fmaf(w2, x2.w, a2.w);
        a3.x = fmaf(w3, x3.x, a3.x); a3.y = fmaf(w3, x3.y, a3.y);
        a3.z = fmaf(w3, x3.z, a3.z); a3.w = fmaf(w3, x3.w, a3.w);
    }
    float4 s;
    s.x = (a0.x + a1.x) + (a2.x + a3.x);
    s.y = (a0.y + a1.y) + (a2.y + a3.y);
    s.z = (a0.z + a1.z) + (a2.z + a3.z);
    s.w = (a0.w + a1.w) + (a2.w + a3.w);

    __shared__ float4 red[4][64];
    red[ts][d4] = s;
    __syncthreads();
    if (ts == 0) {
        float4 r0 = red[0][d4], r1 = red[1][d4], r2 = red[2][d4], r3 = red[3][d4];
        float4 t;
        t.x = (r0.x + r1.x) + (r2.x + r3.x);
        t.y = (r0.y + r1.y) + (r2.y + r3.y);
        t.z = (r0.z + r1.z) + (r2.z + r3.z);
        t.w = (r0.w + r1.w) + (r2.w + r3.w);
        float* c = ctx + b * D_ + d4 * 4;
        atomicAdd(c + 0, t.x);
        atomicAdd(c + 1, t.y);
        atomicAdd(c + 2, t.z);
        atomicAdd(c + 3, t.w);
    }
}

extern "C" void kernel_launch(void* const* d_in, const int* in_sizes, int n_in,
                              void* d_out, int out_size, void* d_ws, size_t ws_size,
                              hipStream_t stream) {
    const float* x    = (const float*)d_in[0];   // [B,T,D]
    const float* W    = (const float*)d_in[1];   // [D,U]
    const float* bias = (const float*)d_in[2];   // [U]
    const float* uvec = (const float*)d_in[3];   // [U,1]

    float* out = (float*)d_out;
    float* ctx = out;            // context: B*D floats
    float* wts = out + B_ * D_;  // attention weights: B*T floats (holds logits between passes)

    unsigned short* whi = (unsigned short*)d_ws;          // 32 KB
    unsigned short* wlo = whi + D_ * U_;                  // 32 KB

    hipMemsetAsync(ctx, 0, B_ * D_ * sizeof(float), stream);

    wprep_kernel<<<D_ * U_ / 256, 256, 0, stream>>>(W, whi, wlo);
    logits_mfma<<<(B_ * T_) / TM, 256, 0, stream>>>(x, whi, wlo, bias, uvec, wts);
    softmax_kernel<<<B_, 256, 0, stream>>>(wts);
    context_kernel<<<dim3(T_ / TC, B_), 256, 0, stream>>>(x, wts, ctx);
}